// Round 8
// baseline (180.884 us; speedup 1.0000x reference)
//
#include <hip/hip_runtime.h>

typedef short  bf16x8 __attribute__((ext_vector_type(8)));
typedef float  f32x4  __attribute__((ext_vector_type(4)));

#define NA   32
#define HID  128
#define TPB  8
#define KSTR 136   // ushort stride, 272B rows, 16B-aligned

__device__ __forceinline__ unsigned short f2bf(float f) {
  unsigned int u = __float_as_uint(f);
  return (unsigned short)((u + 0x7FFFu + ((u >> 16) & 1u)) >> 16);  // RNE
}
__device__ __forceinline__ float bf2f(unsigned short s) {
  return __uint_as_float(((unsigned int)s) << 16);
}
// LDS-only barrier: no vmcnt drain -> prefetch loads ride across.
__device__ __forceinline__ void barrier_lds() {
  asm volatile("s_waitcnt lgkmcnt(0)" ::: "memory");
  __builtin_amdgcn_s_barrier();
  asm volatile("" ::: "memory");
}

__global__ __launch_bounds__(256, 2) void soft_attn_v8(
    const float* __restrict__ h, const float* __restrict__ msg,
    const float* __restrict__ mask,
    const float* __restrict__ qW, const float* __restrict__ qb,
    const float* __restrict__ kW, const float* __restrict__ kb,
    const float* __restrict__ vW, const float* __restrict__ vb,
    const float* __restrict__ dW, const float* __restrict__ db,
    const float* __restrict__ lnw, const float* __restrict__ lnb,
    float* __restrict__ out)
{
  const int t    = threadIdx.x;
  const int lane = t & 63;
  const int w    = t >> 6;        // wave id; owns cols [32w,32w+32), heads {2w,2w+1}
  const int lm   = lane & 15;
  const int lg   = lane >> 4;
  const int n0   = w * 32;
  const int tok0 = blockIdx.x * TPB;

  // Wave-private except s_msgF (2 barriers per PAIR = 1 per token).
  __shared__ __align__(16) short          s_msgF[16 * 64 * 8];     // 16 KB: pair A-frags
  __shared__ __align__(16) unsigned short s_k[2][NA * KSTR];       // 17.4 KB
  __shared__ __align__(16) unsigned short s_v[2][NA * KSTR];       // 17.4 KB (relu'd)
  __shared__ __align__(16) float          s_qall[TPB * HID];       // 4 KB
  __shared__ __align__(16) float          s_p[2][8 * NA];          // 2 KB
  __shared__ __align__(16) short          s_ctxF[4 * 64 * 8];      // 4 KB
  __shared__ __align__(16) char           s_un[4096];              // hF then dall
  short* s_hF   = (short*)s_un;
  float* s_dall = (float*)s_un;
  // ~65 KB -> 2 blocks/CU

  // ---- pair-0 msg prefetch: P[tk][j] = token tk of pair, frags {w, w+4} ----
  f32x4 P[2][2][2];
#pragma unroll
  for (int tk = 0; tk < 2; ++tk)
#pragma unroll
    for (int j = 0; j < 2; ++j) {
      const int f = j * 4 + w, mt = f >> 2, ks = f & 3;
      const float* mp = msg + (size_t)(tok0 + tk) * (NA * HID) + (mt * 16 + lm) * HID + ks * 32 + lg * 8;
      P[tk][j][0] = *(const f32x4*)mp; P[tk][j][1] = *(const f32x4*)(mp + 4);
    }
  // ---- mask preload ----
  float m8[TPB];
#pragma unroll
  for (int i = 0; i < TPB; ++i) m8[i] = mask[(size_t)(tok0 + i) * NA + (lane & 31)];

  // ---- prologue: zero ctxF pads, h frags, q projection ----
#pragma unroll
  for (int j = 0; j < 4; ++j) ((unsigned int*)s_ctxF)[t + 256 * j] = 0u;
  {
    bf16x8 sv;
#pragma unroll
    for (int e = 0; e < 8; ++e) sv[e] = 0;
    if (lm < TPB) {
      const float* hp = h + (size_t)(tok0 + lm) * HID + w * 32 + lg * 8;
      const f32x4 x0 = *(const f32x4*)hp;
      const f32x4 x1 = *(const f32x4*)(hp + 4);
#pragma unroll
      for (int e = 0; e < 4; ++e) { sv[e] = (short)f2bf(x0[e]); sv[4 + e] = (short)f2bf(x1[e]); }
    }
    ((bf16x8*)s_hF)[w * 64 + lane] = sv;
  }
  {
    bf16x8 Bq[2][4];
    float qb2[2];
#pragma unroll
    for (int nt = 0; nt < 2; ++nt) {
      const int col = n0 + nt * 16 + lm;
      qb2[nt] = qb[col];
#pragma unroll
      for (int ks = 0; ks < 4; ++ks) {
        bf16x8 bq;
#pragma unroll
        for (int e = 0; e < 8; ++e)
          bq[e] = (short)f2bf(qW[(size_t)(ks * 32 + lg * 8 + e) * HID + col]);
        Bq[nt][ks] = bq;
      }
    }
    __syncthreads();
    f32x4 accq[2];
#pragma unroll
    for (int nt = 0; nt < 2; ++nt) accq[nt] = (f32x4){qb2[nt], qb2[nt], qb2[nt], qb2[nt]};
#pragma unroll
    for (int ks = 0; ks < 4; ++ks) {
      const bf16x8 a = ((const bf16x8*)s_hF)[ks * 64 + lane];
#pragma unroll
      for (int nt = 0; nt < 2; ++nt)
        accq[nt] = __builtin_amdgcn_mfma_f32_16x16x32_bf16(a, Bq[nt][ks], accq[nt], 0, 0, 0);
    }
#pragma unroll
    for (int nt = 0; nt < 2; ++nt)
#pragma unroll
      for (int r = 0; r < 4; ++r) {
        const int row = lg * 4 + r;
        if (row < TPB) s_qall[row * HID + n0 + nt * 16 + lm] = accq[nt][r];
      }
  }

  // ---- persistent k/v weight fragments (64 VGPR) ----
  bf16x8 Bk[2][4], Bv[2][4];
  float kb2[2], vb2[2];
#pragma unroll
  for (int nt = 0; nt < 2; ++nt) {
    const int col = n0 + nt * 16 + lm;
    kb2[nt] = kb[col]; vb2[nt] = vb[col];
#pragma unroll
    for (int ks = 0; ks < 4; ++ks) {
      bf16x8 bk, bv;
#pragma unroll
      for (int e = 0; e < 8; ++e) {
        const size_t r = (size_t)(ks * 32 + lg * 8 + e) * HID + col;
        bk[e] = (short)f2bf(kW[r]); bv[e] = (short)f2bf(vW[r]);
      }
      Bk[nt][ks] = bk; Bv[nt][ks] = bv;
    }
  }

  // ---- main loop: 4 PAIRS, fully unrolled; 2 barriers/pair ----
#pragma unroll
  for (int pr = 0; pr < 4; ++pr) {
    // stage both tokens' own frags: slot = tk*8 + (j*4+w)
#pragma unroll
    for (int tk = 0; tk < 2; ++tk)
#pragma unroll
      for (int j = 0; j < 2; ++j) {
        const int f = j * 4 + w;
        bf16x8 sv;
#pragma unroll
        for (int e = 0; e < 4; ++e) {
          sv[e]     = (short)f2bf(P[tk][j][0][e]);
          sv[4 + e] = (short)f2bf(P[tk][j][1][e]);
        }
        ((bf16x8*)s_msgF)[(tk * 8 + f) * 64 + lane] = sv;
      }
    // prefetch next pair (rides across both barriers; WAR on P regs is safe in-order)
    if (pr + 1 < 4) {
#pragma unroll
      for (int tk = 0; tk < 2; ++tk)
#pragma unroll
        for (int j = 0; j < 2; ++j) {
          const int f = j * 4 + w, mt = f >> 2, ks = f & 3;
          const float* mp = msg + (size_t)(tok0 + 2 * (pr + 1) + tk) * (NA * HID) + (mt * 16 + lm) * HID + ks * 32 + lg * 8;
          P[tk][j][0] = *(const f32x4*)mp; P[tk][j][1] = *(const f32x4*)(mp + 4);
        }
    }
    barrier_lds();   // B1: all stages visible

    // ---- k/v MFMA for BOTH tokens: 64 MFMAs, 32 independent depth-4 chains ----
    {
      f32x4 kA[2][2], kB[2][2], vA[2][2], vB[2][2];   // [mt][nt]
#pragma unroll
      for (int mt = 0; mt < 2; ++mt)
#pragma unroll
        for (int nt = 0; nt < 2; ++nt) {
          kA[mt][nt] = (f32x4){kb2[nt], kb2[nt], kb2[nt], kb2[nt]};
          kB[mt][nt] = kA[mt][nt];
          vA[mt][nt] = (f32x4){vb2[nt], vb2[nt], vb2[nt], vb2[nt]};
          vB[mt][nt] = vA[mt][nt];
        }
#pragma unroll
      for (int ks = 0; ks < 4; ++ks) {
        const bf16x8 aA0 = ((const bf16x8*)s_msgF)[(0 + ks) * 64 + lane];
        const bf16x8 aA1 = ((const bf16x8*)s_msgF)[(4 + ks) * 64 + lane];
        const bf16x8 aB0 = ((const bf16x8*)s_msgF)[(8 + ks) * 64 + lane];
        const bf16x8 aB1 = ((const bf16x8*)s_msgF)[(12 + ks) * 64 + lane];
#pragma unroll
        for (int nt = 0; nt < 2; ++nt) {
          kA[0][nt] = __builtin_amdgcn_mfma_f32_16x16x32_bf16(aA0, Bk[nt][ks], kA[0][nt], 0, 0, 0);
          kB[0][nt] = __builtin_amdgcn_mfma_f32_16x16x32_bf16(aB0, Bk[nt][ks], kB[0][nt], 0, 0, 0);
          kA[1][nt] = __builtin_amdgcn_mfma_f32_16x16x32_bf16(aA1, Bk[nt][ks], kA[1][nt], 0, 0, 0);
          kB[1][nt] = __builtin_amdgcn_mfma_f32_16x16x32_bf16(aB1, Bk[nt][ks], kB[1][nt], 0, 0, 0);
          vA[0][nt] = __builtin_amdgcn_mfma_f32_16x16x32_bf16(aA0, Bv[nt][ks], vA[0][nt], 0, 0, 0);
          vB[0][nt] = __builtin_amdgcn_mfma_f32_16x16x32_bf16(aB0, Bv[nt][ks], vB[0][nt], 0, 0, 0);
          vA[1][nt] = __builtin_amdgcn_mfma_f32_16x16x32_bf16(aA1, Bv[nt][ks], vA[1][nt], 0, 0, 0);
          vB[1][nt] = __builtin_amdgcn_mfma_f32_16x16x32_bf16(aB1, Bv[nt][ks], vB[1][nt], 0, 0, 0);
        }
      }
#pragma unroll
      for (int mt = 0; mt < 2; ++mt)
#pragma unroll
        for (int nt = 0; nt < 2; ++nt) {
          const int col  = n0 + nt * 16 + lm;
          const int row0 = mt * 16 + lg * 4;
#pragma unroll
          for (int r = 0; r < 4; ++r) {
            s_k[0][(row0 + r) * KSTR + col] = f2bf(kA[mt][nt][r]);
            s_k[1][(row0 + r) * KSTR + col] = f2bf(kB[mt][nt][r]);
            s_v[0][(row0 + r) * KSTR + col] = f2bf(fmaxf(vA[mt][nt][r], 0.f));
            s_v[1][(row0 + r) * KSTR + col] = f2bf(fmaxf(vB[mt][nt][r], 0.f));
          }
        }
    }
    barrier_lds();   // B2: msgF consumed -> next stage may overwrite

    // ---- scores + softmax, both tokens (independent chains) ----
#pragma unroll
    for (int tk = 0; tk < 2; ++tk) {
      const int it = 2 * pr + tk;
      const int hh = lane >> 5, a = lane & 31;
      const int head = 2 * w + hh;
      const f32x4* qr = (const f32x4*)(s_qall + it * HID + head * 16);
      const bf16x8 k0 = *(const bf16x8*)&s_k[tk][a * KSTR + head * 16];
      const bf16x8 k1 = *(const bf16x8*)&s_k[tk][a * KSTR + head * 16 + 8];
      const f32x4 q0 = qr[0], q1 = qr[1], q2 = qr[2], q3 = qr[3];
      float sc = 0.f;
#pragma unroll
      for (int e = 0; e < 4; ++e) {
        sc = fmaf(q0[e], bf2f((unsigned short)k0[e]), sc);
        sc = fmaf(q1[e], bf2f((unsigned short)k0[4 + e]), sc);
        sc = fmaf(q2[e], bf2f((unsigned short)k1[e]), sc);
        sc = fmaf(q3[e], bf2f((unsigned short)k1[4 + e]), sc);
      }
      const float mk = m8[it];
      sc = sc * 0.25f * mk;
      if (sc == 0.0f) sc = -1000000.0f;   // exact reference semantics
      // no max-reduce: |sc_unmasked| << 80; all-masked sum = 32*exp(-80) != 0, p*mk = 0.
      const float ex = __expf(fmaxf(sc, -80.f));
      float sm = ex;
#pragma unroll
      for (int off = 16; off; off >>= 1) sm += __shfl_xor(sm, off);
      s_p[tk][head * NA + a] = ex / sm * mk;
    }

    // ---- PV, both tokens ----
#pragma unroll
    for (int tk = 0; tk < 2; ++tk) {
      const int it = 2 * pr + tk;
      const int o = n0 + (lane >> 1), half = lane & 1;
      const int head = o >> 4;
      const float* pr_ = s_p[tk] + head * NA + half * 16;
      float ctx = 0.f;
#pragma unroll
      for (int i = 0; i < 16; ++i)
        ctx = fmaf(pr_[i], bf2f(s_v[tk][(half * 16 + i) * KSTR + o]), ctx);
      ctx += __shfl_xor(ctx, 1);
      if (half == 0) {
        ((unsigned short*)s_ctxF)[(((o >> 5) * 64) + ((o >> 3) & 3) * 16 + it) * 8 + (o & 7)] = f2bf(ctx);
      }
    }
  }
  __syncthreads();   // ctxF complete (cross-wave for d-proj)

  // ---- batched d projection ----
  {
    bf16x8 Bd[2][4];
    float db2[2];
#pragma unroll
    for (int nt = 0; nt < 2; ++nt) {
      const int col = n0 + nt * 16 + lm;
      db2[nt] = db[col];
#pragma unroll
      for (int ks = 0; ks < 4; ++ks) {
        bf16x8 bd;
#pragma unroll
        for (int e = 0; e < 8; ++e)
          bd[e] = (short)f2bf(dW[(size_t)(ks * 32 + lg * 8 + e) * HID + col]);
        Bd[nt][ks] = bd;
      }
    }
    f32x4 accd[2];
#pragma unroll
    for (int nt = 0; nt < 2; ++nt) accd[nt] = (f32x4){db2[nt], db2[nt], db2[nt], db2[nt]};
#pragma unroll
    for (int ks = 0; ks < 4; ++ks) {
      const bf16x8 a = ((const bf16x8*)s_ctxF)[ks * 64 + lane];
#pragma unroll
      for (int nt = 0; nt < 2; ++nt)
        accd[nt] = __builtin_amdgcn_mfma_f32_16x16x32_bf16(a, Bd[nt][ks], accd[nt], 0, 0, 0);
    }
#pragma unroll
    for (int nt = 0; nt < 2; ++nt)
#pragma unroll
      for (int r = 0; r < 4; ++r) {
        const int row = lg * 4 + r;
        if (row < TPB) s_dall[row * HID + n0 + nt * 16 + lm] = accd[nt][r];
      }
  }
  __syncthreads();

  // ---- residual + layernorm ----
  {
    const int row = t >> 5, seg = t & 31;
    const f32x4 xd = *(const f32x4*)(s_dall + row * HID + seg * 4);
    const f32x4 xh = *(const f32x4*)(h + (size_t)(tok0 + row) * HID + seg * 4);
    float x[4];
    float s1 = 0.f, s2 = 0.f;
#pragma unroll
    for (int e = 0; e < 4; ++e) { x[e] = xd[e] + xh[e]; s1 += x[e]; s2 += x[e] * x[e]; }
#pragma unroll
    for (int off = 16; off; off >>= 1) { s1 += __shfl_xor(s1, off); s2 += __shfl_xor(s2, off); }
    const float u   = s1 * (1.f / 128.f);
    const float var = s2 * (1.f / 128.f) - u * u;
    const float rs  = rsqrtf(var + 1e-12f);
    const f32x4 w4 = *(const f32x4*)(lnw + seg * 4);
    const f32x4 b4 = *(const f32x4*)(lnb + seg * 4);
    f32x4 y;
#pragma unroll
    for (int e = 0; e < 4; ++e) y[e] = w4[e] * ((x[e] - u) * rs) + b4[e];
    *(f32x4*)(out + (size_t)(tok0 + row) * HID + seg * 4) = y;
  }
}

extern "C" void kernel_launch(void* const* d_in, const int* in_sizes, int n_in,
                              void* d_out, int out_size, void* d_ws, size_t ws_size,
                              hipStream_t stream) {
  const float* h    = (const float*)d_in[0];
  const float* msg  = (const float*)d_in[1];
  const float* mask = (const float*)d_in[2];
  const float* qW   = (const float*)d_in[3];
  const float* qb   = (const float*)d_in[4];
  const float* kW   = (const float*)d_in[5];
  const float* kb   = (const float*)d_in[6];
  const float* vW   = (const float*)d_in[7];
  const float* vb   = (const float*)d_in[8];
  const float* dW   = (const float*)d_in[9];
  const float* db   = (const float*)d_in[10];
  const float* lnw  = (const float*)d_in[11];
  const float* lnb  = (const float*)d_in[12];
  float* out = (float*)d_out;

  const int n_tokens = in_sizes[0] / HID;   // 16384
  const int nblocks  = n_tokens / TPB;      // 2048
  soft_attn_v8<<<nblocks, 256, 0, stream>>>(
      h, msg, mask, qW, qb, kW, kb, vW, vb, dW, db, lnw, lnb, out);
}

// Round 9
// 146.666 us; speedup vs baseline: 1.2333x; 1.2333x over previous
//
#include <hip/hip_runtime.h>

typedef short  bf16x8  __attribute__((ext_vector_type(8)));
typedef short  short4v __attribute__((ext_vector_type(4)));
typedef float  f32x4   __attribute__((ext_vector_type(4)));

#define NA   32
#define HID  128
#define TPB  8
#define KSTR 136   // s_k ushort row stride (272B, 16B-aligned)
#define VSTR 40    // s_vT ushort row stride (80B, 16B-aligned)

__device__ __forceinline__ unsigned short f2bf(float f) {
  unsigned int u = __float_as_uint(f);
  return (unsigned short)((u + 0x7FFFu + ((u >> 16) & 1u)) >> 16);  // RNE
}
__device__ __forceinline__ float bf2f(unsigned short s) {
  return __uint_as_float(((unsigned int)s) << 16);
}
// LDS-only barrier: no vmcnt drain -> global prefetch rides across.
__device__ __forceinline__ void barrier_lds() {
  asm volatile("s_waitcnt lgkmcnt(0)" ::: "memory");
  __builtin_amdgcn_s_barrier();
  asm volatile("" ::: "memory");
}

__global__ __launch_bounds__(256, 2) void soft_attn_v9(
    const float* __restrict__ h, const float* __restrict__ msg,
    const float* __restrict__ mask,
    const float* __restrict__ qW, const float* __restrict__ qb,
    const float* __restrict__ kW, const float* __restrict__ kb,
    const float* __restrict__ vW, const float* __restrict__ vb,
    const float* __restrict__ dW, const float* __restrict__ db,
    const float* __restrict__ lnw, const float* __restrict__ lnb,
    float* __restrict__ out)
{
  const int t    = threadIdx.x;
  const int lane = t & 63;
  const int w    = t >> 6;        // wave id; owns cols [32w,32w+32), heads {2w,2w+1}
  const int lm   = lane & 15;
  const int lg   = lane >> 4;
  const int n0   = w * 32;
  const int tok0 = blockIdx.x * TPB;

  // Wave-private except s_msgF (1 barrier/token, double-buffered).
  __shared__ __align__(16) short          s_msgF[2][8 * 64 * 8];  // 16 KB
  __shared__ __align__(16) unsigned short s_k[NA * KSTR];         // 8704 B  k[a][o]
  __shared__ __align__(16) unsigned short s_vT[HID * VSTR];       // 10240 B v[o][a]
  __shared__ __align__(16) float          s_qall[TPB * HID];      // 4 KB
  __shared__ __align__(16) float          s_p[8 * NA];            // 1 KB (f32 for b128 PV reads)
  __shared__ __align__(16) short          s_ctxF[4 * 64 * 8];     // 4 KB
  __shared__ __align__(16) char           s_un[4096];             // hF then dall
  short* s_hF   = (short*)s_un;
  float* s_dall = (float*)s_un;
  // total ~48.6 KB

  // ---- depth-2 msg prefetch: P[d] = token parity d, frags {w, w+4} ----
  f32x4 P[2][2][2];
#pragma unroll
  for (int d = 0; d < 2; ++d)
#pragma unroll
    for (int j = 0; j < 2; ++j) {
      const int f = j * 4 + w, mt = f >> 2, ks = f & 3;
      const float* mp = msg + (size_t)(tok0 + d) * (NA * HID) + (mt * 16 + lm) * HID + ks * 32 + lg * 8;
      P[d][j][0] = *(const f32x4*)mp; P[d][j][1] = *(const f32x4*)(mp + 4);
    }
  // ---- mask preload ----
  float m8[TPB];
#pragma unroll
  for (int i = 0; i < TPB; ++i) m8[i] = mask[(size_t)(tok0 + i) * NA + (lane & 31)];

  // ---- prologue: zero ctxF pads, h frags, q projection ----
#pragma unroll
  for (int j = 0; j < 4; ++j) ((unsigned int*)s_ctxF)[t + 256 * j] = 0u;
  {
    bf16x8 sv;
#pragma unroll
    for (int e = 0; e < 8; ++e) sv[e] = 0;
    if (lm < TPB) {
      const float* hp = h + (size_t)(tok0 + lm) * HID + w * 32 + lg * 8;
      const f32x4 x0 = *(const f32x4*)hp;
      const f32x4 x1 = *(const f32x4*)(hp + 4);
#pragma unroll
      for (int e = 0; e < 4; ++e) { sv[e] = (short)f2bf(x0[e]); sv[4 + e] = (short)f2bf(x1[e]); }
    }
    ((bf16x8*)s_hF)[w * 64 + lane] = sv;
  }
  {
    bf16x8 Bq[2][4];
    float qb2[2];
#pragma unroll
    for (int nt = 0; nt < 2; ++nt) {
      const int col = n0 + nt * 16 + lm;
      qb2[nt] = qb[col];
#pragma unroll
      for (int ks = 0; ks < 4; ++ks) {
        bf16x8 bq;
#pragma unroll
        for (int e = 0; e < 8; ++e)
          bq[e] = (short)f2bf(qW[(size_t)(ks * 32 + lg * 8 + e) * HID + col]);
        Bq[nt][ks] = bq;
      }
    }
    __syncthreads();
    f32x4 accq[2];
#pragma unroll
    for (int nt = 0; nt < 2; ++nt) accq[nt] = (f32x4){qb2[nt], qb2[nt], qb2[nt], qb2[nt]};
#pragma unroll
    for (int ks = 0; ks < 4; ++ks) {
      const bf16x8 a = ((const bf16x8*)s_hF)[ks * 64 + lane];
#pragma unroll
      for (int nt = 0; nt < 2; ++nt)
        accq[nt] = __builtin_amdgcn_mfma_f32_16x16x32_bf16(a, Bq[nt][ks], accq[nt], 0, 0, 0);
    }
#pragma unroll
    for (int nt = 0; nt < 2; ++nt)
#pragma unroll
      for (int r = 0; r < 4; ++r) {
        const int row = lg * 4 + r;
        if (row < TPB) s_qall[row * HID + n0 + nt * 16 + lm] = accq[nt][r];
      }
  }

  // ---- persistent weight frags + biases ----
  bf16x8 Bk[2][4], Bv[2][4];
  f32x4 kb4[2];            // k bias along o = n0+nt*16+lg*4+r (swapped-C rows)
  float vb2[2];
#pragma unroll
  for (int nt = 0; nt < 2; ++nt) {
    const int col = n0 + nt * 16 + lm;
    kb4[nt] = *(const f32x4*)(kb + n0 + nt * 16 + lg * 4);
    vb2[nt] = vb[col];
#pragma unroll
    for (int ks = 0; ks < 4; ++ks) {
      bf16x8 bk, bv;
#pragma unroll
      for (int e = 0; e < 8; ++e) {
        const size_t r = (size_t)(ks * 32 + lg * 8 + e) * HID + col;
        bk[e] = (short)f2bf(kW[r]); bv[e] = (short)f2bf(vW[r]);
      }
      Bk[nt][ks] = bk; Bv[nt][ks] = bv;
    }
  }

  // ---- main loop (fully unrolled, 1 LDS barrier/token) ----
#pragma unroll
  for (int it = 0; it < TPB; ++it) {
    const int tok = tok0 + it;
    const int buf = it & 1;

    // stage own frags {w, w+4}
#pragma unroll
    for (int j = 0; j < 2; ++j) {
      const int f = j * 4 + w;
      bf16x8 sv;
#pragma unroll
      for (int e = 0; e < 4; ++e) {
        sv[e]     = (short)f2bf(P[buf][j][0][e]);
        sv[4 + e] = (short)f2bf(P[buf][j][1][e]);
      }
      ((bf16x8*)(&s_msgF[buf][0]))[f * 64 + lane] = sv;
    }
    // re-issue prefetch for it+2 (consumed 2 iters later; rides across barrier)
    if (it + 2 < TPB) {
#pragma unroll
      for (int j = 0; j < 2; ++j) {
        const int f = j * 4 + w, mt = f >> 2, ks = f & 3;
        const float* mp = msg + (size_t)(tok + 2) * (NA * HID) + (mt * 16 + lm) * HID + ks * 32 + lg * 8;
        P[buf][j][0] = *(const f32x4*)mp; P[buf][j][1] = *(const f32x4*)(mp + 4);
      }
    }
    barrier_lds();   // msgF visible (dbuf covers laggards on buf^1)

    // ---- k projection, SWAPPED (A=Bk, B=msg): lane -> k[a=mt*16+lm][o=n0+nt*16+lg*4+r]
    //      4 packed b64 writes into row-major s_k
    {
      f32x4 ck[2][2];  // [nt][mt]
#pragma unroll
      for (int nt = 0; nt < 2; ++nt)
#pragma unroll
        for (int mt = 0; mt < 2; ++mt) ck[nt][mt] = kb4[nt];
#pragma unroll
      for (int ks = 0; ks < 4; ++ks) {
        const bf16x8 a0 = ((const bf16x8*)(&s_msgF[buf][0]))[ks * 64 + lane];
        const bf16x8 a1 = ((const bf16x8*)(&s_msgF[buf][0]))[(4 + ks) * 64 + lane];
#pragma unroll
        for (int nt = 0; nt < 2; ++nt) {
          ck[nt][0] = __builtin_amdgcn_mfma_f32_16x16x32_bf16(Bk[nt][ks], a0, ck[nt][0], 0, 0, 0);
          ck[nt][1] = __builtin_amdgcn_mfma_f32_16x16x32_bf16(Bk[nt][ks], a1, ck[nt][1], 0, 0, 0);
        }
      }
#pragma unroll
      for (int nt = 0; nt < 2; ++nt)
#pragma unroll
        for (int mt = 0; mt < 2; ++mt) {
          short4v kp;
#pragma unroll
          for (int r = 0; r < 4; ++r) kp[r] = (short)f2bf(ck[nt][mt][r]);
          *(short4v*)&s_k[(mt * 16 + lm) * KSTR + n0 + nt * 16 + lg * 4] = kp;
        }
    }
    // ---- v projection, normal (A=msg, B=Bv): lane -> v[a=mt*16+lg*4+r][o=n0+nt*16+lm]
    //      4 packed b64 writes into transposed s_vT[o][a]
    {
      f32x4 cv[2][2];  // [mt][nt]
#pragma unroll
      for (int mt = 0; mt < 2; ++mt)
#pragma unroll
        for (int nt = 0; nt < 2; ++nt) cv[mt][nt] = (f32x4){vb2[nt], vb2[nt], vb2[nt], vb2[nt]};
#pragma unroll
      for (int ks = 0; ks < 4; ++ks) {
        const bf16x8 a0 = ((const bf16x8*)(&s_msgF[buf][0]))[ks * 64 + lane];
        const bf16x8 a1 = ((const bf16x8*)(&s_msgF[buf][0]))[(4 + ks) * 64 + lane];
#pragma unroll
        for (int nt = 0; nt < 2; ++nt) {
          cv[0][nt] = __builtin_amdgcn_mfma_f32_16x16x32_bf16(a0, Bv[nt][ks], cv[0][nt], 0, 0, 0);
          cv[1][nt] = __builtin_amdgcn_mfma_f32_16x16x32_bf16(a1, Bv[nt][ks], cv[1][nt], 0, 0, 0);
        }
      }
#pragma unroll
      for (int mt = 0; mt < 2; ++mt)
#pragma unroll
        for (int nt = 0; nt < 2; ++nt) {
          short4v vp;
#pragma unroll
          for (int r = 0; r < 4; ++r) vp[r] = (short)f2bf(fmaxf(cv[mt][nt][r], 0.f));  // relu
          *(short4v*)&s_vT[(n0 + nt * 16 + lm) * VSTR + mt * 16 + lg * 4] = vp;
        }
    }

    // ---- scores + softmax (max-free; bounded scores), p -> f32 LDS ----
    {
      const int hh = lane >> 5, a = lane & 31;
      const int head = 2 * w + hh;
      const f32x4* qr = (const f32x4*)(s_qall + it * HID + head * 16);
      const bf16x8 k0 = *(const bf16x8*)&s_k[a * KSTR + head * 16];
      const bf16x8 k1 = *(const bf16x8*)&s_k[a * KSTR + head * 16 + 8];
      const f32x4 q0 = qr[0], q1 = qr[1], q2 = qr[2], q3 = qr[3];
      float sc = 0.f;
#pragma unroll
      for (int e = 0; e < 4; ++e) {
        sc = fmaf(q0[e], bf2f((unsigned short)k0[e]), sc);
        sc = fmaf(q1[e], bf2f((unsigned short)k0[4 + e]), sc);
        sc = fmaf(q2[e], bf2f((unsigned short)k1[e]), sc);
        sc = fmaf(q3[e], bf2f((unsigned short)k1[4 + e]), sc);
      }
      const float mk = m8[it];
      sc = sc * 0.25f * mk;
      if (sc == 0.0f) sc = -1000000.0f;   // exact reference semantics
      // no max-reduce: |sc_unmasked| << 80; all-masked sum = 32*exp(-80) != 0, p*mk = 0.
      const float ex = __expf(fmaxf(sc, -80.f));
      float sm = ex;
#pragma unroll
      for (int off = 16; off; off >>= 1) sm += __shfl_xor(sm, off);
      s_p[head * NA + a] = ex / sm * mk;
    }

    // ---- PV vectorized: thread (o = n0+lane>>1, half = lane&1) ----
    //      2 b128 vT reads + 4 b128 p reads (broadcast) + depth-8 fmaf + 1 shfl
    {
      const int o = n0 + (lane >> 1), half = lane & 1;
      const int head = o >> 4;
      const bf16x8 v0 = *(const bf16x8*)&s_vT[o * VSTR + half * 16];
      const bf16x8 v1 = *(const bf16x8*)&s_vT[o * VSTR + half * 16 + 8];
      const f32x4* pp = (const f32x4*)&s_p[head * NA + half * 16];
      const f32x4 p0 = pp[0], p1 = pp[1], p2 = pp[2], p3 = pp[3];
      float c0 = 0.f, c1 = 0.f;
#pragma unroll
      for (int e = 0; e < 4; ++e) {
        c0 = fmaf(p0[e], bf2f((unsigned short)v0[e]), c0);
        c1 = fmaf(p1[e], bf2f((unsigned short)v0[4 + e]), c1);
        c0 = fmaf(p2[e], bf2f((unsigned short)v1[e]), c0);
        c1 = fmaf(p3[e], bf2f((unsigned short)v1[4 + e]), c1);
      }
      float ctx = c0 + c1;
      ctx += __shfl_xor(ctx, 1);
      if (half == 0) {
        ((unsigned short*)s_ctxF)[(((o >> 5) * 64) + ((o >> 3) & 3) * 16 + it) * 8 + (o & 7)] = f2bf(ctx);
      }
    }
  }
  __syncthreads();   // ctxF complete (cross-wave for d-proj)

  // ---- batched d projection ----
  {
    bf16x8 Bd[2][4];
    float db2[2];
#pragma unroll
    for (int nt = 0; nt < 2; ++nt) {
      const int col = n0 + nt * 16 + lm;
      db2[nt] = db[col];
#pragma unroll
      for (int ks = 0; ks < 4; ++ks) {
        bf16x8 bd;
#pragma unroll
        for (int e = 0; e < 8; ++e)
          bd[e] = (short)f2bf(dW[(size_t)(ks * 32 + lg * 8 + e) * HID + col]);
        Bd[nt][ks] = bd;
      }
    }
    f32x4 accd[2];
#pragma unroll
    for (int nt = 0; nt < 2; ++nt) accd[nt] = (f32x4){db2[nt], db2[nt], db2[nt], db2[nt]};
#pragma unroll
    for (int ks = 0; ks < 4; ++ks) {
      const bf16x8 a = ((const bf16x8*)s_ctxF)[ks * 64 + lane];
#pragma unroll
      for (int nt = 0; nt < 2; ++nt)
        accd[nt] = __builtin_amdgcn_mfma_f32_16x16x32_bf16(a, Bd[nt][ks], accd[nt], 0, 0, 0);
    }
#pragma unroll
    for (int nt = 0; nt < 2; ++nt)
#pragma unroll
      for (int r = 0; r < 4; ++r) {
        const int row = lg * 4 + r;
        if (row < TPB) s_dall[row * HID + n0 + nt * 16 + lm] = accd[nt][r];
      }
  }
  __syncthreads();

  // ---- residual + layernorm ----
  {
    const int row = t >> 5, seg = t & 31;
    const f32x4 xd = *(const f32x4*)(s_dall + row * HID + seg * 4);
    const f32x4 xh = *(const f32x4*)(h + (size_t)(tok0 + row) * HID + seg * 4);
    float x[4];
    float s1 = 0.f, s2 = 0.f;
#pragma unroll
    for (int e = 0; e < 4; ++e) { x[e] = xd[e] + xh[e]; s1 += x[e]; s2 += x[e] * x[e]; }
#pragma unroll
    for (int off = 16; off; off >>= 1) { s1 += __shfl_xor(s1, off); s2 += __shfl_xor(s2, off); }
    const float u   = s1 * (1.f / 128.f);
    const float var = s2 * (1.f / 128.f) - u * u;
    const float rs  = rsqrtf(var + 1e-12f);
    const f32x4 w4 = *(const f32x4*)(lnw + seg * 4);
    const f32x4 b4 = *(const f32x4*)(lnb + seg * 4);
    f32x4 y;
#pragma unroll
    for (int e = 0; e < 4; ++e) y[e] = w4[e] * ((x[e] - u) * rs) + b4[e];
    *(f32x4*)(out + (size_t)(tok0 + row) * HID + seg * 4) = y;
  }
}

extern "C" void kernel_launch(void* const* d_in, const int* in_sizes, int n_in,
                              void* d_out, int out_size, void* d_ws, size_t ws_size,
                              hipStream_t stream) {
  const float* h    = (const float*)d_in[0];
  const float* msg  = (const float*)d_in[1];
  const float* mask = (const float*)d_in[2];
  const float* qW   = (const float*)d_in[3];
  const float* qb   = (const float*)d_in[4];
  const float* kW   = (const float*)d_in[5];
  const float* kb   = (const float*)d_in[6];
  const float* vW   = (const float*)d_in[7];
  const float* vb   = (const float*)d_in[8];
  const float* dW   = (const float*)d_in[9];
  const float* db   = (const float*)d_in[10];
  const float* lnw  = (const float*)d_in[11];
  const float* lnb  = (const float*)d_in[12];
  float* out = (float*)d_out;

  const int n_tokens = in_sizes[0] / HID;   // 16384
  const int nblocks  = n_tokens / TPB;      // 2048
  soft_attn_v9<<<nblocks, 256, 0, stream>>>(
      h, msg, mask, qW, qb, kW, kb, vW, vb, dW, db, lnw, lnb, out);
}

// Round 10
// 141.799 us; speedup vs baseline: 1.2756x; 1.0343x over previous
//
#include <hip/hip_runtime.h>

typedef short  bf16x8 __attribute__((ext_vector_type(8)));
typedef float  f32x4  __attribute__((ext_vector_type(4)));

#define NA   32
#define HID  128
#define TPB  8
#define KSTR 132   // fp32 row stride for s_k/s_v (528B rows, 16B-aligned)

__device__ __forceinline__ unsigned short f2bf(float f) {
  unsigned int u = __float_as_uint(f);
  return (unsigned short)((u + 0x7FFFu + ((u >> 16) & 1u)) >> 16);  // RNE
}
// LDS-only barrier: does NOT drain vmcnt -> prefetch loads ride across.
__device__ __forceinline__ void barrier_lds() {
  asm volatile("s_waitcnt lgkmcnt(0)" ::: "memory");
  __builtin_amdgcn_s_barrier();
  asm volatile("" ::: "memory");
}

__global__ __launch_bounds__(256, 2) void soft_attn_v10(
    const float* __restrict__ h, const float* __restrict__ msg,
    const float* __restrict__ mask,
    const float* __restrict__ qW, const float* __restrict__ qb,
    const float* __restrict__ kW, const float* __restrict__ kb,
    const float* __restrict__ vW, const float* __restrict__ vb,
    const float* __restrict__ dW, const float* __restrict__ db,
    const float* __restrict__ lnw, const float* __restrict__ lnb,
    float* __restrict__ out)
{
  const int t    = threadIdx.x;
  const int lane = t & 63;
  const int w    = t >> 6;        // wave id; owns output cols [32w, 32w+32)
  const int lm   = lane & 15;
  const int lg   = lane >> 4;
  const int n0   = w * 32;
  const int tok0 = blockIdx.x * TPB;

  __shared__ __align__(16) short s_msgF[2][8 * 64 * 8];   // 16 KB msg A-frags, dbuf
  __shared__ __align__(16) float s_k[NA * KSTR];          // 16.9 KB fp32 k
  __shared__ __align__(16) float s_v[NA * KSTR];          // 16.9 KB fp32 v (relu'd)
  __shared__ __align__(16) float s_qall[TPB * HID];       // 4 KB
  __shared__ __align__(16) float s_hall[TPB * HID];       // 4 KB (residual)
  __shared__ __align__(16) float s_p[8 * NA];             // 1 KB
  __shared__ __align__(16) short s_ctxF[4 * 64 * 8];      // 4 KB ctx A-frags
  __shared__ __align__(16) char  s_un[4096];              // hF then dall
  short* s_hF   = (short*)s_un;
  float* s_dall = (float*)s_un;
  // ~67 KB -> 2 blocks/CU

  // ---- prologue: h fp32 + frags, msg(tok0) prefetch, mask, zero ctxF ----
  ((f32x4*)s_hall)[t] = ((const f32x4*)(h + (size_t)tok0 * HID))[t];
#pragma unroll
  for (int j = 0; j < 4; ++j) ((unsigned int*)s_ctxF)[t + 256 * j] = 0u;
  {
    bf16x8 sv;
#pragma unroll
    for (int e = 0; e < 8; ++e) sv[e] = 0;
    if (lm < TPB) {
      const float* hp = h + (size_t)(tok0 + lm) * HID + w * 32 + lg * 8;
      const f32x4 x0 = *(const f32x4*)hp;
      const f32x4 x1 = *(const f32x4*)(hp + 4);
#pragma unroll
      for (int e = 0; e < 4; ++e) { sv[e] = (short)f2bf(x0[e]); sv[4 + e] = (short)f2bf(x1[e]); }
    }
    ((bf16x8*)s_hF)[w * 64 + lane] = sv;
  }
  f32x4 P[2][2];  // depth-1 prefetch: frags {w, w+4} of current staged token
#pragma unroll
  for (int j = 0; j < 2; ++j) {
    const int f = j * 4 + w, mt = f >> 2, ks = f & 3;
    const float* mp = msg + (size_t)tok0 * (NA * HID) + (mt * 16 + lm) * HID + ks * 32 + lg * 8;
    P[j][0] = *(const f32x4*)mp; P[j][1] = *(const f32x4*)(mp + 4);
  }
  float m8[TPB];
#pragma unroll
  for (int i = 0; i < TPB; ++i) m8[i] = mask[(size_t)(tok0 + i) * NA + (lane & 31)];

  // ---- batched q projection (Bq transient) ----
  {
    bf16x8 Bq[2][4];
    float qb2[2];
#pragma unroll
    for (int nt = 0; nt < 2; ++nt) {
      const int col = n0 + nt * 16 + lm;
      qb2[nt] = qb[col];
#pragma unroll
      for (int ks = 0; ks < 4; ++ks) {
        bf16x8 bq;
#pragma unroll
        for (int e = 0; e < 8; ++e)
          bq[e] = (short)f2bf(qW[(size_t)(ks * 32 + lg * 8 + e) * HID + col]);
        Bq[nt][ks] = bq;
      }
    }
    __syncthreads();   // hF + ctxF-zero ready
    f32x4 accq[2];
#pragma unroll
    for (int nt = 0; nt < 2; ++nt) accq[nt] = (f32x4){qb2[nt], qb2[nt], qb2[nt], qb2[nt]};
#pragma unroll
    for (int ks = 0; ks < 4; ++ks) {
      const bf16x8 a = ((const bf16x8*)s_hF)[ks * 64 + lane];
#pragma unroll
      for (int nt = 0; nt < 2; ++nt)
        accq[nt] = __builtin_amdgcn_mfma_f32_16x16x32_bf16(a, Bq[nt][ks], accq[nt], 0, 0, 0);
    }
#pragma unroll
    for (int nt = 0; nt < 2; ++nt)
#pragma unroll
      for (int r = 0; r < 4; ++r) {
        const int row = lg * 4 + r;
        if (row < TPB) s_qall[row * HID + n0 + nt * 16 + lm] = accq[nt][r];
      }
  }

  // ---- persistent k/v weight fragments (64 VGPR) ----
  bf16x8 Bk[2][4], Bv[2][4];
  float kb2[2], vb2[2];
#pragma unroll
  for (int nt = 0; nt < 2; ++nt) {
    const int col = n0 + nt * 16 + lm;
    kb2[nt] = kb[col]; vb2[nt] = vb[col];
#pragma unroll
    for (int ks = 0; ks < 4; ++ks) {
      bf16x8 bk, bv;
#pragma unroll
      for (int e = 0; e < 8; ++e) {
        const size_t r = (size_t)(ks * 32 + lg * 8 + e) * HID + col;
        bk[e] = (short)f2bf(kW[r]); bv[e] = (short)f2bf(vW[r]);
      }
      Bk[nt][ks] = bk; Bv[nt][ks] = bv;
    }
  }

  // ---- main loop: stage | B1(full) | prefetch, kvMFMA | B2(lds) | scores | B3(lds) | PV ----
#pragma unroll
  for (int it = 0; it < TPB; ++it) {
    const int tok = tok0 + it;
    const int buf = it & 1;

    // stage own frags {w, w+4} from P
#pragma unroll
    for (int j = 0; j < 2; ++j) {
      const int f = j * 4 + w;
      bf16x8 sv;
#pragma unroll
      for (int e = 0; e < 4; ++e) {
        sv[e]     = (short)f2bf(P[j][0][e]);
        sv[4 + e] = (short)f2bf(P[j][1][e]);
      }
      ((bf16x8*)(&s_msgF[buf][0]))[f * 64 + lane] = sv;
    }
    __syncthreads();   // B1: msgF visible (full sync; nothing significant in flight)

    // prefetch msg(tok+1): issued here, rides across B2/B3 (LDS-only barriers),
    // consumed at next iteration's stage via counted vmcnt.
    if (it + 1 < TPB) {
#pragma unroll
      for (int j = 0; j < 2; ++j) {
        const int f = j * 4 + w, mt = f >> 2, ks = f & 3;
        const float* mp = msg + (size_t)(tok + 1) * (NA * HID) + (mt * 16 + lm) * HID + ks * 32 + lg * 8;
        P[j][0] = *(const f32x4*)mp; P[j][1] = *(const f32x4*)(mp + 4);
      }
    }

    // k/v projection: 32 MFMA (16x16x32), fp32 stores (no f2bf on this path)
    {
      f32x4 ak[2][2], av[2][2];   // [mt][nt]
#pragma unroll
      for (int mt = 0; mt < 2; ++mt)
#pragma unroll
        for (int nt = 0; nt < 2; ++nt) {
          ak[mt][nt] = (f32x4){kb2[nt], kb2[nt], kb2[nt], kb2[nt]};
          av[mt][nt] = (f32x4){vb2[nt], vb2[nt], vb2[nt], vb2[nt]};
        }
#pragma unroll
      for (int ks = 0; ks < 4; ++ks) {
        const bf16x8 a0 = ((const bf16x8*)(&s_msgF[buf][0]))[ks * 64 + lane];        // mt=0
        const bf16x8 a1 = ((const bf16x8*)(&s_msgF[buf][0]))[(4 + ks) * 64 + lane];  // mt=1
#pragma unroll
        for (int nt = 0; nt < 2; ++nt) {
          ak[0][nt] = __builtin_amdgcn_mfma_f32_16x16x32_bf16(a0, Bk[nt][ks], ak[0][nt], 0, 0, 0);
          av[0][nt] = __builtin_amdgcn_mfma_f32_16x16x32_bf16(a0, Bv[nt][ks], av[0][nt], 0, 0, 0);
          ak[1][nt] = __builtin_amdgcn_mfma_f32_16x16x32_bf16(a1, Bk[nt][ks], ak[1][nt], 0, 0, 0);
          av[1][nt] = __builtin_amdgcn_mfma_f32_16x16x32_bf16(a1, Bv[nt][ks], av[1][nt], 0, 0, 0);
        }
      }
#pragma unroll
      for (int mt = 0; mt < 2; ++mt)
#pragma unroll
        for (int nt = 0; nt < 2; ++nt) {
          const int col  = n0 + nt * 16 + lm;
          const int row0 = mt * 16 + lg * 4;
#pragma unroll
          for (int r = 0; r < 4; ++r) {
            s_k[(row0 + r) * KSTR + col] = ak[mt][nt][r];
            s_v[(row0 + r) * KSTR + col] = fmaxf(av[mt][nt][r], 0.f);  // relu
          }
        }
    }
    barrier_lds();   // B2: k/v visible (prefetch stays in flight)

    // scores + max-free masked softmax: thread (head = t>>5, a = t&31)
    {
      const int head = t >> 5, a = t & 31;
      const f32x4* qr = (const f32x4*)(s_qall + it * HID + head * 16);
      const f32x4* kr = (const f32x4*)(s_k + a * KSTR + head * 16);
      const f32x4 q0 = qr[0], q1 = qr[1], q2 = qr[2], q3 = qr[3];
      const f32x4 k0 = kr[0], k1 = kr[1], k2 = kr[2], k3 = kr[3];
      float sc = 0.f;
#pragma unroll
      for (int e = 0; e < 4; ++e) {
        sc = fmaf(q0[e], k0[e], sc);
        sc = fmaf(q1[e], k1[e], sc);
        sc = fmaf(q2[e], k2[e], sc);
        sc = fmaf(q3[e], k3[e], sc);
      }
      const float mk = m8[it];
      sc = sc * 0.25f * mk;
      if (sc == 0.0f) sc = -1000000.0f;   // exact reference semantics
      // no max-reduce: |sc_unmasked| << 80; all-masked sum = 32*exp(-80) != 0 -> p*mk = 0.
      const float ex = __expf(fmaxf(sc, -80.f));
      float sm = ex;
#pragma unroll
      for (int off = 16; off; off >>= 1) sm += __shfl_xor(sm, off);
      s_p[head * NA + a] = ex / sm * mk;  // softmax * mask
    }
    barrier_lds();   // B3: s_p visible (prefetch still in flight)

    // PV: 256 threads, thread (o = t>>1, half = t&1) sums 16 a's; shfl-combine
    {
      const int o = t >> 1, half = t & 1;
      const int head = o >> 4;
      const float* pr = s_p + head * NA + half * 16;
      float ctx = 0.f;
#pragma unroll
      for (int i = 0; i < 16; ++i)
        ctx = fmaf(pr[i], s_v[(half * 16 + i) * KSTR + o], ctx);
      ctx += __shfl_xor(ctx, 1);
      if (half == 0) {
        // ctx A-frag: frag = o>>5, kg = (o>>3)&3, m = it, e = o&7
        ((unsigned short*)s_ctxF)[(((o >> 5) * 64) + ((o >> 3) & 3) * 16 + it) * 8 + (o & 7)] = f2bf(ctx);
      }
    }
    // no barrier: next stage writes msgF[buf^1] only; k/v readers all passed B2
  }
  __syncthreads();   // ctxF complete

  // ---- batched d projection (Bd transient) ----
  {
    bf16x8 Bd[2][4];
    float db2[2];
#pragma unroll
    for (int nt = 0; nt < 2; ++nt) {
      const int col = n0 + nt * 16 + lm;
      db2[nt] = db[col];
#pragma unroll
      for (int ks = 0; ks < 4; ++ks) {
        bf16x8 bd;
#pragma unroll
        for (int e = 0; e < 8; ++e)
          bd[e] = (short)f2bf(dW[(size_t)(ks * 32 + lg * 8 + e) * HID + col]);
        Bd[nt][ks] = bd;
      }
    }
    f32x4 accd[2];
#pragma unroll
    for (int nt = 0; nt < 2; ++nt) accd[nt] = (f32x4){db2[nt], db2[nt], db2[nt], db2[nt]};
#pragma unroll
    for (int ks = 0; ks < 4; ++ks) {
      const bf16x8 a = ((const bf16x8*)s_ctxF)[ks * 64 + lane];
#pragma unroll
      for (int nt = 0; nt < 2; ++nt)
        accd[nt] = __builtin_amdgcn_mfma_f32_16x16x32_bf16(a, Bd[nt][ks], accd[nt], 0, 0, 0);
    }
    __syncthreads();  // hF (union) dead before dall writes
#pragma unroll
    for (int nt = 0; nt < 2; ++nt)
#pragma unroll
      for (int r = 0; r < 4; ++r) {
        const int row = lg * 4 + r;
        if (row < TPB) s_dall[row * HID + n0 + nt * 16 + lm] = accd[nt][r];
      }
  }
  __syncthreads();

  // ---- residual + layernorm (32 lanes per token row) ----
  {
    const int row = t >> 5, seg = t & 31;
    const f32x4 xd = *(const f32x4*)(s_dall + row * HID + seg * 4);
    const f32x4 xh = *(const f32x4*)(s_hall + row * HID + seg * 4);
    float x[4];
    float s1 = 0.f, s2 = 0.f;
#pragma unroll
    for (int e = 0; e < 4; ++e) { x[e] = xd[e] + xh[e]; s1 += x[e]; s2 += x[e] * x[e]; }
#pragma unroll
    for (int off = 16; off; off >>= 1) { s1 += __shfl_xor(s1, off); s2 += __shfl_xor(s2, off); }
    const float u   = s1 * (1.f / 128.f);
    const float var = s2 * (1.f / 128.f) - u * u;
    const float rs  = rsqrtf(var + 1e-12f);
    const f32x4 w4 = *(const f32x4*)(lnw + seg * 4);
    const f32x4 b4 = *(const f32x4*)(lnb + seg * 4);
    f32x4 y;
#pragma unroll
    for (int e = 0; e < 4; ++e) y[e] = w4[e] * ((x[e] - u) * rs) + b4[e];
    *(f32x4*)(out + (size_t)(tok0 + row) * HID + seg * 4) = y;
  }
}

extern "C" void kernel_launch(void* const* d_in, const int* in_sizes, int n_in,
                              void* d_out, int out_size, void* d_ws, size_t ws_size,
                              hipStream_t stream) {
  const float* h    = (const float*)d_in[0];
  const float* msg  = (const float*)d_in[1];
  const float* mask = (const float*)d_in[2];
  const float* qW   = (const float*)d_in[3];
  const float* qb   = (const float*)d_in[4];
  const float* kW   = (const float*)d_in[5];
  const float* kb   = (const float*)d_in[6];
  const float* vW   = (const float*)d_in[7];
  const float* vb   = (const float*)d_in[8];
  const float* dW   = (const float*)d_in[9];
  const float* db   = (const float*)d_in[10];
  const float* lnw  = (const float*)d_in[11];
  const float* lnb  = (const float*)d_in[12];
  float* out = (float*)d_out;

  const int n_tokens = in_sizes[0] / HID;   // 16384
  const int nblocks  = n_tokens / TPB;      // 2048
  soft_attn_v10<<<nblocks, 256, 0, stream>>>(
      h, msg, mask, qW, qb, kW, kb, vW, vb, dW, db, lnw, lnb, out);
}